// Round 1
// baseline (713.363 us; speedup 1.0000x reference)
//
#include <hip/hip_runtime.h>
#include <math.h>

#define RES 192
#define RANK 8
#define NI 128

// dst[c][r] = src[r][c]
__global__ void transpose_kernel(const float* __restrict__ src, float* __restrict__ dst, int R, int C){
    int idx = blockIdx.x*blockDim.x + threadIdx.x;
    if (idx < R*C){
        int r = idx / C, c = idx - r*C;
        dst[c*R + r] = src[r*C + c];
    }
}

__device__ __forceinline__ void prep_idx(float c, int size, int& i0, float& f){
    float idx = (c + 1.0f)*0.5f*(float)(size-1);
    idx = fminf(fmaxf(idx, 0.0f), (float)(size-1));
    int ii = (int)idx;               // idx >= 0, so trunc == floor
    if (ii > size-2) ii = size-2;
    i0 = ii;
    f = idx - (float)ii;
}

__device__ __forceinline__ float wred64(float v){
    #pragma unroll
    for (int o=32;o>0;o>>=1) v += __shfl_down(v, o, 64);
    return v;
}

__launch_bounds__(128, 2)
__global__ void nerf_fused(
    const float* __restrict__ rays_o, const float* __restrict__ rays_d,
    const float* __restrict__ Gxy, const float* __restrict__ Gxz, const float* __restrict__ Gyz,
    const float* __restrict__ F_grid,
    const float* __restrict__ sW0, const float* __restrict__ W1T, const float* __restrict__ sW2,
    const float* __restrict__ cW0, const float* __restrict__ cW1T, const float* __restrict__ cW2,
    float* __restrict__ out)
{
    const int ray = blockIdx.x;
    const int i   = threadIdx.x;

    __shared__ float shRow[NI*33];   // per-thread scratch row (stride 33 -> conflict-free)
    __shared__ float sf[NI];
    __shared__ float partial[8];

    const float ox = rays_o[ray*3+0], oy = rays_o[ray*3+1], oz = rays_o[ray*3+2];
    const float dx = rays_d[ray*3+0], dy = rays_d[ray*3+1], dz = rays_d[ray*3+2];

    // ray-AABB intersection (replicates reference op-order)
    float sdx = (fabsf(dx) < 1e-9f) ? 1e-9f : dx;
    float sdy = (fabsf(dy) < 1e-9f) ? 1e-9f : dy;
    float sdz = (fabsf(dz) < 1e-9f) ? 1e-9f : dz;
    float t1x = (-1.3f - ox)/sdx, t2x = (1.3f - ox)/sdx;
    float t1y = (-1.3f - oy)/sdy, t2y = (1.3f - oy)/sdy;
    float t1z = (-1.3f - oz)/sdz, t2z = (1.3f - oz)/sdz;
    float tmin = fmaxf(fminf(t1x,t2x), fmaxf(fminf(t1y,t2y), fminf(t1z,t2z)));
    float tmax = fminf(fmaxf(t1x,t2x), fminf(fmaxf(t1y,t2y), fmaxf(t1z,t2z)));
    float nearv = fmaxf(tmin, 0.0f);

    float ts0 = nearv + (float)i     * 0.0352f;
    float ts1 = nearv + (float)(i+1) * 0.0352f;
    float tmid = 0.5f*(ts0+ts1);
    float dist = ts1 - ts0;
    float px = ox + tmid*dx, py = oy + tmid*dy, pz = oz + tmid*dz;
    bool mask = (fabsf(px)<=1.3f) && (fabsf(py)<=1.3f) && (fabsf(pz)<=1.3f)
              && (tmid<=tmax) && (tmax>tmin);

    float sigma = 0.0f, rr = 0.0f, rg = 0.0f, rb = 0.0f;

    if (mask){
        // p = ((pts/R + 1) * RES/2) * (2/RES) - 1   (replicated exactly)
        float p0 = (px/1.3f + 1.0f)*192.0f/2.0f*2.0f/192.0f - 1.0f;
        float p1 = (py/1.3f + 1.0f)*192.0f/2.0f*2.0f/192.0f - 1.0f;
        float p2 = (pz/1.3f + 1.0f)*192.0f/2.0f*2.0f/192.0f - 1.0f;

        int x0, y0, z0; float fx, fy, fz;
        prep_idx(p0, RES, x0, fx);
        prep_idx(p1, RES, y0, fy);
        prep_idx(p2, RES, z0, fz);

        // low-rank triplane trilinear: grid[z,y,x,ch] = sum_r Gxy[z,y,ch,r]*Gxz[z,x,ch,r]*Gyz[y,x,ch,r]
        float gv0=0.f, gv1=0.f, gv2=0.f;
        #pragma unroll
        for (int zc=0; zc<2; zc++){
            const int zi = z0 + zc;
            const float wz = zc ? fz : (1.0f - fz);
            #pragma unroll
            for (int yc=0; yc<2; yc++){
                const int yi = y0 + yc;
                const float wy = yc ? fy : (1.0f - fy);
                const float* __restrict__ pxy = Gxy + (size_t)((zi*RES + yi)*3)*RANK;
                const float wzy = wz*wy;
                #pragma unroll
                for (int xc=0; xc<2; xc++){
                    const int xi = x0 + xc;
                    const float wx = xc ? fx : (1.0f - fx);
                    const float* __restrict__ pxz = Gxz + (size_t)((zi*RES + xi)*3)*RANK;
                    const float* __restrict__ pyz = Gyz + (size_t)((yi*RES + xi)*3)*RANK;
                    const float w = wzy*wx;
                    float s0=0.f,s1=0.f,s2=0.f;
                    #pragma unroll
                    for (int r=0;r<RANK;r++){
                        s0 = fmaf(pxy[r]     *pxz[r],      pyz[r],      s0);
                        s1 = fmaf(pxy[8+r]   *pxz[8+r],    pyz[8+r],    s1);
                        s2 = fmaf(pxy[16+r]  *pxz[16+r],   pyz[16+r],   s2);
                    }
                    gv0 = fmaf(w, s0, gv0);
                    gv1 = fmaf(w, s1, gv1);
                    gv2 = fmaf(w, s2, gv2);
                }
            }
        }

        // F_grid trilinear at coords (gv0->x, gv1->y, gv2->z), vol (32,32,32,32)
        int a0,b0,c0; float fa,fb,fc;
        prep_idx(gv2, 32, a0, fa);
        prep_idx(gv1, 32, b0, fb);
        prep_idx(gv0, 32, c0, fc);
        float Fv[32];
        #pragma unroll
        for (int k=0;k<32;k++) Fv[k]=0.f;
        #pragma unroll
        for (int zc=0; zc<2; zc++){
            const int zi = a0+zc; const float wz = zc ? fa : 1.f-fa;
            #pragma unroll
            for (int yc=0; yc<2; yc++){
                const int yi = b0+yc; const float wy = yc ? fb : 1.f-fb;
                #pragma unroll
                for (int xc=0; xc<2; xc++){
                    const int xi = c0+xc; const float wx = xc ? fc : 1.f-fc;
                    const float w = wz*wy*wx;
                    const float* __restrict__ pf = F_grid + (size_t)(((zi*32)+yi)*32+xi)*32;
                    #pragma unroll
                    for (int k=0;k<32;k++) Fv[k] = fmaf(w, pf[k], Fv[k]);
                }
            }
        }

        // stash Fv so the layer-1 reduction loop can index it dynamically
        #pragma unroll
        for (int k=0;k<32;k++) shRow[i*33+k] = Fv[k];

        // sigma MLP layer 1: 32 -> 128 (weights wave-uniform -> scalar loads)
        float h1[128];
        #pragma unroll
        for (int j=0;j<128;j++) h1[j]=0.f;
        for (int k=0;k<32;k++){
            const float fk = shRow[i*33+k];
            const float* __restrict__ w0 = sW0 + k*128;
            #pragma unroll
            for (int j=0;j<128;j++) h1[j] = fmaf(fk, w0[j], h1[j]);
        }
        #pragma unroll
        for (int j=0;j<128;j++) h1[j] = fmaxf(h1[j], 0.f);

        // layer 2 (via W1T) fused with layer 3 (sW2): 128 -> 128 -> 16
        float out16[16];
        #pragma unroll
        for (int o=0;o<16;o++) out16[o]=0.f;
        for (int k=0;k<128;k++){
            const float* __restrict__ w1 = W1T + k*128;
            float q0=0.f,q1=0.f,q2=0.f,q3=0.f;
            #pragma unroll
            for (int j=0;j<128;j+=4){
                q0 = fmaf(h1[j+0], w1[j+0], q0);
                q1 = fmaf(h1[j+1], w1[j+1], q1);
                q2 = fmaf(h1[j+2], w1[j+2], q2);
                q3 = fmaf(h1[j+3], w1[j+3], q3);
            }
            const float h2 = fmaxf((q0+q1)+(q2+q3), 0.f);
            const float* __restrict__ w2 = sW2 + k*16;
            #pragma unroll
            for (int o=0;o<16;o++) out16[o] = fmaf(h2, w2[o], out16[o]);
        }
        sigma = fmaxf(out16[0], 0.f);

        // SH basis of normalized ray dir + out16[1:] -> ci[31] in LDS row
        const float dn = sqrtf(dx*dx+dy*dy+dz*dz);
        const float X = dx/dn, Y = dy/dn, Z = dz/dn;
        const float X2=X*X, Y2=Y*Y, Z2=Z*Z;
        float sh[16];
        sh[0]= 0.28209479177387814f;
        sh[1]=-0.48860251190291987f*Y;
        sh[2]= 0.48860251190291987f*Z;
        sh[3]=-0.48860251190291987f*X;
        sh[4]= 1.0925484305920792f*X*Y;
        sh[5]=-1.0925484305920792f*Y*Z;
        sh[6]= 0.94617469575756f*Z2 - 0.31539156525252f;
        sh[7]=-1.0925484305920792f*X*Z;
        sh[8]= 0.5462742152960396f*(X2-Y2);
        sh[9]= 0.5900435899266435f*Y*(-3.0f*X2+Y2);
        sh[10]=2.890611442640554f*X*Y*Z;
        sh[11]=0.4570457994644657f*Y*(1.0f-5.0f*Z2);
        sh[12]=0.3731763325901154f*Z*(5.0f*Z2-3.0f);
        sh[13]=0.4570457994644657f*X*(1.0f-5.0f*Z2);
        sh[14]=1.445305721320277f*Z*(X2-Y2);
        sh[15]=0.5900435899266435f*X*(-X2+3.0f*Y2);
        #pragma unroll
        for (int k=0;k<16;k++) shRow[i*33+k] = sh[k];
        #pragma unroll
        for (int k=0;k<15;k++) shRow[i*33+16+k] = out16[1+k];

        // color layer 1: 31 -> 64
        float c1[64];
        #pragma unroll
        for (int j=0;j<64;j++) c1[j]=0.f;
        for (int k=0;k<31;k++){
            const float ck = shRow[i*33+k];
            const float* __restrict__ w = cW0 + k*64;
            #pragma unroll
            for (int j=0;j<64;j++) c1[j] = fmaf(ck, w[j], c1[j]);
        }
        #pragma unroll
        for (int j=0;j<64;j++) c1[j] = fmaxf(c1[j], 0.f);

        // color layer 2 (cW1T) fused with layer 3 (cW2): 64 -> 64 -> 3
        float cr=0.f, cg=0.f, cb=0.f;
        for (int k=0;k<64;k++){
            const float* __restrict__ w = cW1T + k*64;
            float q0=0.f,q1=0.f,q2=0.f,q3=0.f;
            #pragma unroll
            for (int j=0;j<64;j+=4){
                q0=fmaf(c1[j+0],w[j+0],q0);
                q1=fmaf(c1[j+1],w[j+1],q1);
                q2=fmaf(c1[j+2],w[j+2],q2);
                q3=fmaf(c1[j+3],w[j+3],q3);
            }
            const float c2 = fmaxf((q0+q1)+(q2+q3), 0.f);
            const float* __restrict__ w2 = cW2 + k*3;
            cr = fmaf(c2, w2[0], cr);
            cg = fmaf(c2, w2[1], cg);
            cb = fmaf(c2, w2[2], cb);
        }
        rr = 1.0f/(1.0f+expf(-cr));
        rg = 1.0f/(1.0f+expf(-cg));
        rb = 1.0f/(1.0f+expf(-cb));
    }

    // volume compositing: exclusive product scan of (1 - alpha + 1e-10)
    float alpha = 1.0f - expf(-sigma*dist);     // masked lanes: sigma=0 -> alpha=0 exactly
    sf[i] = 1.0f - alpha + 1e-10f;
    __syncthreads();
    #pragma unroll
    for (int off=1; off<NI; off<<=1){
        float u = (i>=off) ? sf[i-off] : 1.0f;
        float v = sf[i];
        __syncthreads();
        sf[i] = u*v;
        __syncthreads();
    }
    float T = (i==0) ? 1.0f : sf[i-1];
    float w = alpha*T;

    float v0 = wred64(w*rr);
    float v1 = wred64(w*rg);
    float v2 = wred64(w*rb);
    float v3 = wred64(w);
    if ((i&63)==0){
        int wid = i>>6;
        partial[wid*4+0]=v0; partial[wid*4+1]=v1; partial[wid*4+2]=v2; partial[wid*4+3]=v3;
    }
    __syncthreads();
    if (i==0){
        float acc = partial[3]+partial[7];
        float bg = 1.0f - acc;
        out[ray*3+0] = partial[0]+partial[4] + bg;
        out[ray*3+1] = partial[1]+partial[5] + bg;
        out[ray*3+2] = partial[2]+partial[6] + bg;
    }
}

extern "C" void kernel_launch(void* const* d_in, const int* in_sizes, int n_in,
                              void* d_out, int out_size, void* d_ws, size_t ws_size,
                              hipStream_t stream){
    const float* rays_o = (const float*)d_in[0];
    const float* rays_d = (const float*)d_in[1];
    const float* Gxy    = (const float*)d_in[2];
    const float* Gxz    = (const float*)d_in[3];
    const float* Gyz    = (const float*)d_in[4];
    const float* F_grid = (const float*)d_in[5];
    const float* sW0    = (const float*)d_in[6];
    const float* sW1    = (const float*)d_in[7];
    const float* sW2    = (const float*)d_in[8];
    const float* cW0    = (const float*)d_in[9];
    const float* cW1    = (const float*)d_in[10];
    const float* cW2    = (const float*)d_in[11];

    float* W1T  = (float*)d_ws;              // 128*128 floats
    float* cW1T = W1T + 128*128;             // 64*64 floats

    transpose_kernel<<<(128*128+255)/256, 256, 0, stream>>>(sW1, W1T, 128, 128);
    transpose_kernel<<<(64*64+255)/256,   256, 0, stream>>>(cW1, cW1T, 64, 64);
    nerf_fused<<<2048, 128, 0, stream>>>(rays_o, rays_d, Gxy, Gxz, Gyz, F_grid,
                                         sW0, W1T, sW2, cW0, cW1T, cW2, (float*)d_out);
}

// Round 2
// 187.615 us; speedup vs baseline: 3.8023x; 3.8023x over previous
//
#include <hip/hip_runtime.h>
#include <math.h>

#define RES 192
#define RANK 8
#define NI 128
#define LW 136   // padded LDS row width (shorts); 136*2=272B = 17*16B -> b128-aligned rows

typedef __attribute__((ext_vector_type(8))) short short8;
typedef __attribute__((ext_vector_type(4))) float floatx4;

// packed-weight offsets in shorts (each fragment chunk: 64 lanes * 8 bf16)
#define OFF_SW0 0        // 8 ntiles * 1 kstep  * 512 = 4096
#define OFF_SW1 4096     // 8 * 4 * 512 = 16384
#define OFF_SW2 20480    // 1 * 4 * 512 = 2048
#define OFF_CW0 22528    // 4 * 1 * 512 = 2048
#define OFF_CW1 24576    // 4 * 2 * 512 = 4096
#define OFF_CW2 28672    // 1 * 2 * 512 = 1024
#define PACK_TOTAL 29696

__device__ __forceinline__ short f2bf(float x){
    unsigned u = __float_as_uint(x);
    unsigned r = (u + 0x7FFFu + ((u >> 16) & 1u)) >> 16;   // RTNE
    return (short)r;
}

__device__ __forceinline__ void prep_idx(float c, int size, int& i0, float& f){
    float idx = (c + 1.0f)*0.5f*(float)(size-1);
    idx = fminf(fmaxf(idx, 0.0f), (float)(size-1));
    int ii = (int)idx;               // idx >= 0, trunc == floor
    if (ii > size-2) ii = size-2;
    i0 = ii;
    f = idx - (float)ii;
}

__device__ __forceinline__ float wred64(float v){
    #pragma unroll
    for (int o=32;o>0;o>>=1) v += __shfl_down(v, o, 64);
    return v;
}

// Pack all 6 weight matrices into MFMA B-fragment order:
// chunk (ntile,kstep): 64 lanes x 8 bf16; element j of lane: W[k][n],
// k = kstep*32 + (lane>>4)*8 + j, n = ntile*16 + (lane&15); zero-pad outside.
__global__ void pack_all(const float* __restrict__ sW0, const float* __restrict__ sW1,
                         const float* __restrict__ sW2, const float* __restrict__ cW0,
                         const float* __restrict__ cW1, const float* __restrict__ cW2,
                         short* __restrict__ dst){
    int e = blockIdx.x*256 + threadIdx.x;
    if (e >= PACK_TOTAL) return;
    const float* src; int K, N, ksteps, base;
    if      (e < OFF_SW1){ src=sW0; K=32;  N=128; ksteps=1; base=OFF_SW0; }
    else if (e < OFF_SW2){ src=sW1; K=128; N=128; ksteps=4; base=OFF_SW1; }
    else if (e < OFF_CW0){ src=sW2; K=128; N=16;  ksteps=4; base=OFF_SW2; }
    else if (e < OFF_CW1){ src=cW0; K=31;  N=64;  ksteps=1; base=OFF_CW0; }
    else if (e < OFF_CW2){ src=cW1; K=64;  N=64;  ksteps=2; base=OFF_CW1; }
    else                 { src=cW2; K=64;  N=3;   ksteps=2; base=OFF_CW2; }
    int i = e - base;
    int j = i & 7, lane = (i>>3)&63, t = i>>9;
    int ks = t % ksteps, nt = t / ksteps;
    int k = ks*32 + (lane>>4)*8 + j;
    int n = nt*16 + (lane&15);
    float v = (k < K && n < N) ? src[k*N + n] : 0.0f;
    dst[e] = f2bf(v);
}

__launch_bounds__(256, 2)
__global__ void nerf_mfma(
    const float* __restrict__ rays_o, const float* __restrict__ rays_d,
    const float* __restrict__ Gxy, const float* __restrict__ Gxz, const float* __restrict__ Gyz,
    const float* __restrict__ F_grid, const short* __restrict__ Wp,
    float* __restrict__ out)
{
    __shared__ short buf[128*LW];        // activations, bf16, row = sample
    __shared__ float sigmaArr[128];
    __shared__ float rgbArr[128*3];
    __shared__ float wtot[2];
    __shared__ float partial[8];

    const int tid  = threadIdx.x;
    const int lane = tid & 63;
    const int wv   = tid >> 6;           // wave 0..3
    const int ray  = blockIdx.x;

    const float ox = rays_o[ray*3+0], oy = rays_o[ray*3+1], oz = rays_o[ray*3+2];
    const float dx = rays_d[ray*3+0], dy = rays_d[ray*3+1], dz = rays_d[ray*3+2];

    // ray-AABB (reference op-order)
    float sdx = (fabsf(dx) < 1e-9f) ? 1e-9f : dx;
    float sdy = (fabsf(dy) < 1e-9f) ? 1e-9f : dy;
    float sdz = (fabsf(dz) < 1e-9f) ? 1e-9f : dz;
    float t1x = (-1.3f - ox)/sdx, t2x = (1.3f - ox)/sdx;
    float t1y = (-1.3f - oy)/sdy, t2y = (1.3f - oy)/sdy;
    float t1z = (-1.3f - oz)/sdz, t2z = (1.3f - oz)/sdz;
    float tmin = fmaxf(fminf(t1x,t2x), fmaxf(fminf(t1y,t2y), fminf(t1z,t2z)));
    float tmax = fminf(fmaxf(t1x,t2x), fminf(fmaxf(t1y,t2y), fmaxf(t1z,t2z)));
    float nearv = fmaxf(tmin, 0.0f);

    // ---------------- phase 0: interpolation (threads 0..127, sample = tid) --------------
    if (tid < 128){
        float ts0 = nearv + (float)tid     * 0.0352f;
        float ts1 = nearv + (float)(tid+1) * 0.0352f;
        float tmid = 0.5f*(ts0+ts1);
        float px = ox + tmid*dx, py = oy + tmid*dy, pz = oz + tmid*dz;

        float p0 = (px/1.3f + 1.0f)*192.0f/2.0f*2.0f/192.0f - 1.0f;
        float p1 = (py/1.3f + 1.0f)*192.0f/2.0f*2.0f/192.0f - 1.0f;
        float p2 = (pz/1.3f + 1.0f)*192.0f/2.0f*2.0f/192.0f - 1.0f;

        int x0, y0, z0; float fx, fy, fz;
        prep_idx(p0, RES, x0, fx);
        prep_idx(p1, RES, y0, fy);
        prep_idx(p2, RES, z0, fz);

        float gv0=0.f, gv1=0.f, gv2=0.f;
        #pragma unroll
        for (int zc=0; zc<2; zc++){
            const int zi = z0 + zc;
            const float wz = zc ? fz : (1.0f - fz);
            #pragma unroll
            for (int yc=0; yc<2; yc++){
                const int yi = y0 + yc;
                const float wy = yc ? fy : (1.0f - fy);
                const float* __restrict__ pxy = Gxy + (size_t)((zi*RES + yi)*3)*RANK;
                const float wzy = wz*wy;
                #pragma unroll
                for (int xc=0; xc<2; xc++){
                    const int xi = x0 + xc;
                    const float wx = xc ? fx : (1.0f - fx);
                    const float* __restrict__ pxz = Gxz + (size_t)((zi*RES + xi)*3)*RANK;
                    const float* __restrict__ pyz = Gyz + (size_t)((yi*RES + xi)*3)*RANK;
                    const float w = wzy*wx;
                    float s0=0.f,s1=0.f,s2=0.f;
                    #pragma unroll
                    for (int r=0;r<RANK;r++){
                        s0 = fmaf(pxy[r]    *pxz[r],    pyz[r],    s0);
                        s1 = fmaf(pxy[8+r]  *pxz[8+r],  pyz[8+r],  s1);
                        s2 = fmaf(pxy[16+r] *pxz[16+r], pyz[16+r], s2);
                    }
                    gv0 = fmaf(w, s0, gv0);
                    gv1 = fmaf(w, s1, gv1);
                    gv2 = fmaf(w, s2, gv2);
                }
            }
        }

        int a0,b0,c0; float fa,fb,fc;
        prep_idx(gv2, 32, a0, fa);
        prep_idx(gv1, 32, b0, fb);
        prep_idx(gv0, 32, c0, fc);
        float Fv[32];
        #pragma unroll
        for (int k=0;k<32;k++) Fv[k]=0.f;
        #pragma unroll
        for (int zc=0; zc<2; zc++){
            const int zi = a0+zc; const float wz = zc ? fa : 1.f-fa;
            #pragma unroll
            for (int yc=0; yc<2; yc++){
                const int yi = b0+yc; const float wy = yc ? fb : 1.f-fb;
                #pragma unroll
                for (int xc=0; xc<2; xc++){
                    const int xi = c0+xc; const float wx = xc ? fc : 1.f-fc;
                    const float w = wz*wy*wx;
                    const float* __restrict__ pf = F_grid + (size_t)(((zi*32)+yi)*32+xi)*32;
                    #pragma unroll
                    for (int k=0;k<32;k++) Fv[k] = fmaf(w, pf[k], Fv[k]);
                }
            }
        }
        #pragma unroll
        for (int q=0;q<4;q++){
            short8 v;
            #pragma unroll
            for (int j=0;j<8;j++) v[j] = f2bf(Fv[q*8+j]);
            *(short8*)&buf[tid*LW + q*8] = v;
        }
    }
    __syncthreads();

    // ---------------- MLP phases: wave wv owns rows [wv*32, wv*32+32) ----------------
    const int rowbase = wv*32;
    const int col  = lane & 15;
    const int quad = lane >> 4;
    const int ar0  = rowbase + col;        // A row, mtile 0
    const int ar1  = ar0 + 16;             // A row, mtile 1

    // L1: 32 -> 128, relu
    {
        short8 a0 = *(const short8*)&buf[ar0*LW + quad*8];
        short8 a1 = *(const short8*)&buf[ar1*LW + quad*8];
        const short8* W = (const short8*)(Wp + OFF_SW0);
        #pragma unroll
        for (int nt=0; nt<8; nt++){
            short8 b = W[nt*64 + lane];
            floatx4 c0v = {0.f,0.f,0.f,0.f}, c1v = {0.f,0.f,0.f,0.f};
            c0v = __builtin_amdgcn_mfma_f32_16x16x32_bf16(a0, b, c0v, 0,0,0);
            c1v = __builtin_amdgcn_mfma_f32_16x16x32_bf16(a1, b, c1v, 0,0,0);
            #pragma unroll
            for (int r=0;r<4;r++){
                int row0 = rowbase + quad*4 + r;
                buf[row0*LW      + nt*16 + col] = f2bf(fmaxf(c0v[r],0.f));
                buf[(row0+16)*LW + nt*16 + col] = f2bf(fmaxf(c1v[r],0.f));
            }
        }
    }
    __syncthreads();

    // L2: 128 -> 128, relu
    {
        short8 A0[4], A1[4];
        #pragma unroll
        for (int ks=0;ks<4;ks++){
            A0[ks] = *(const short8*)&buf[ar0*LW + ks*32 + quad*8];
            A1[ks] = *(const short8*)&buf[ar1*LW + ks*32 + quad*8];
        }
        const short8* W = (const short8*)(Wp + OFF_SW1);
        #pragma unroll
        for (int nt=0; nt<8; nt++){
            floatx4 c0v = {0.f,0.f,0.f,0.f}, c1v = {0.f,0.f,0.f,0.f};
            #pragma unroll
            for (int ks=0;ks<4;ks++){
                short8 b = W[(nt*4+ks)*64 + lane];
                c0v = __builtin_amdgcn_mfma_f32_16x16x32_bf16(A0[ks], b, c0v, 0,0,0);
                c1v = __builtin_amdgcn_mfma_f32_16x16x32_bf16(A1[ks], b, c1v, 0,0,0);
            }
            #pragma unroll
            for (int r=0;r<4;r++){
                int row0 = rowbase + quad*4 + r;
                buf[row0*LW      + nt*16 + col] = f2bf(fmaxf(c0v[r],0.f));
                buf[(row0+16)*LW + nt*16 + col] = f2bf(fmaxf(c1v[r],0.f));
            }
        }
    }
    __syncthreads();

    // L3: 128 -> 16 (no relu). col0 -> sigmaArr (f32), cols 1..15 -> buf cols 16..30.
    // Then sh16 (ray-uniform) -> buf cols 0..15.
    {
        short8 A0[4], A1[4];
        #pragma unroll
        for (int ks=0;ks<4;ks++){
            A0[ks] = *(const short8*)&buf[ar0*LW + ks*32 + quad*8];
            A1[ks] = *(const short8*)&buf[ar1*LW + ks*32 + quad*8];
        }
        const short8* W = (const short8*)(Wp + OFF_SW2);
        floatx4 c0v = {0.f,0.f,0.f,0.f}, c1v = {0.f,0.f,0.f,0.f};
        #pragma unroll
        for (int ks=0;ks<4;ks++){
            short8 b = W[ks*64 + lane];
            c0v = __builtin_amdgcn_mfma_f32_16x16x32_bf16(A0[ks], b, c0v, 0,0,0);
            c1v = __builtin_amdgcn_mfma_f32_16x16x32_bf16(A1[ks], b, c1v, 0,0,0);
        }
        #pragma unroll
        for (int r=0;r<4;r++){
            int row0 = rowbase + quad*4 + r;
            if (col == 0){
                sigmaArr[row0]    = c0v[r];
                sigmaArr[row0+16] = c1v[r];
            } else {
                buf[row0*LW      + 15 + col] = f2bf(c0v[r]);
                buf[(row0+16)*LW + 15 + col] = f2bf(c1v[r]);
            }
        }
        // SH basis (ray-uniform)
        const float dn = sqrtf(dx*dx+dy*dy+dz*dz);
        const float X = dx/dn, Y = dy/dn, Z = dz/dn;
        const float X2=X*X, Y2=Y*Y, Z2=Z*Z;
        float sh[16];
        sh[0]= 0.28209479177387814f;
        sh[1]=-0.48860251190291987f*Y;
        sh[2]= 0.48860251190291987f*Z;
        sh[3]=-0.48860251190291987f*X;
        sh[4]= 1.0925484305920792f*X*Y;
        sh[5]=-1.0925484305920792f*Y*Z;
        sh[6]= 0.94617469575756f*Z2 - 0.31539156525252f;
        sh[7]=-1.0925484305920792f*X*Z;
        sh[8]= 0.5462742152960396f*(X2-Y2);
        sh[9]= 0.5900435899266435f*Y*(-3.0f*X2+Y2);
        sh[10]=2.890611442640554f*X*Y*Z;
        sh[11]=0.4570457994644657f*Y*(1.0f-5.0f*Z2);
        sh[12]=0.3731763325901154f*Z*(5.0f*Z2-3.0f);
        sh[13]=0.4570457994644657f*X*(1.0f-5.0f*Z2);
        sh[14]=1.445305721320277f*Z*(X2-Y2);
        sh[15]=0.5900435899266435f*X*(-X2+3.0f*Y2);
        if (lane < 32){
            int row = rowbase + lane;
            #pragma unroll
            for (int k=0;k<16;k++) buf[row*LW + k] = f2bf(sh[k]);
        }
    }
    __syncthreads();

    // CL1: 31(pad32) -> 64, relu  (col 31 garbage x zero weight row = 0)
    {
        short8 a0 = *(const short8*)&buf[ar0*LW + quad*8];
        short8 a1 = *(const short8*)&buf[ar1*LW + quad*8];
        const short8* W = (const short8*)(Wp + OFF_CW0);
        #pragma unroll
        for (int nt=0; nt<4; nt++){
            short8 b = W[nt*64 + lane];
            floatx4 c0v = {0.f,0.f,0.f,0.f}, c1v = {0.f,0.f,0.f,0.f};
            c0v = __builtin_amdgcn_mfma_f32_16x16x32_bf16(a0, b, c0v, 0,0,0);
            c1v = __builtin_amdgcn_mfma_f32_16x16x32_bf16(a1, b, c1v, 0,0,0);
            #pragma unroll
            for (int r=0;r<4;r++){
                int row0 = rowbase + quad*4 + r;
                buf[row0*LW      + nt*16 + col] = f2bf(fmaxf(c0v[r],0.f));
                buf[(row0+16)*LW + nt*16 + col] = f2bf(fmaxf(c1v[r],0.f));
            }
        }
    }
    __syncthreads();

    // CL2: 64 -> 64, relu
    {
        short8 A0[2], A1[2];
        #pragma unroll
        for (int ks=0;ks<2;ks++){
            A0[ks] = *(const short8*)&buf[ar0*LW + ks*32 + quad*8];
            A1[ks] = *(const short8*)&buf[ar1*LW + ks*32 + quad*8];
        }
        const short8* W = (const short8*)(Wp + OFF_CW1);
        #pragma unroll
        for (int nt=0; nt<4; nt++){
            floatx4 c0v = {0.f,0.f,0.f,0.f}, c1v = {0.f,0.f,0.f,0.f};
            #pragma unroll
            for (int ks=0;ks<2;ks++){
                short8 b = W[(nt*2+ks)*64 + lane];
                c0v = __builtin_amdgcn_mfma_f32_16x16x32_bf16(A0[ks], b, c0v, 0,0,0);
                c1v = __builtin_amdgcn_mfma_f32_16x16x32_bf16(A1[ks], b, c1v, 0,0,0);
            }
            #pragma unroll
            for (int r=0;r<4;r++){
                int row0 = rowbase + quad*4 + r;
                buf[row0*LW      + nt*16 + col] = f2bf(fmaxf(c0v[r],0.f));
                buf[(row0+16)*LW + nt*16 + col] = f2bf(fmaxf(c1v[r],0.f));
            }
        }
    }
    __syncthreads();

    // CL3: 64 -> 3 (cols 0..2 of 16), no relu -> rgbArr (f32)
    {
        short8 A0[2], A1[2];
        #pragma unroll
        for (int ks=0;ks<2;ks++){
            A0[ks] = *(const short8*)&buf[ar0*LW + ks*32 + quad*8];
            A1[ks] = *(const short8*)&buf[ar1*LW + ks*32 + quad*8];
        }
        const short8* W = (const short8*)(Wp + OFF_CW2);
        floatx4 c0v = {0.f,0.f,0.f,0.f}, c1v = {0.f,0.f,0.f,0.f};
        #pragma unroll
        for (int ks=0;ks<2;ks++){
            short8 b = W[ks*64 + lane];
            c0v = __builtin_amdgcn_mfma_f32_16x16x32_bf16(A0[ks], b, c0v, 0,0,0);
            c1v = __builtin_amdgcn_mfma_f32_16x16x32_bf16(A1[ks], b, c1v, 0,0,0);
        }
        if (col < 3){
            #pragma unroll
            for (int r=0;r<4;r++){
                int row0 = rowbase + quad*4 + r;
                rgbArr[row0*3 + col]      = c0v[r];
                rgbArr[(row0+16)*3 + col] = c1v[r];
            }
        }
    }
    __syncthreads();

    // ---------------- compositing (threads 0..127, sample = tid) ----------------
    float alpha = 0.f, rr = 0.f, rg = 0.f, rb = 0.f;
    if (tid < 128){
        float ts0 = nearv + (float)tid     * 0.0352f;
        float ts1 = nearv + (float)(tid+1) * 0.0352f;
        float tmid = 0.5f*(ts0+ts1);
        float dist = ts1 - ts0;
        float px = ox + tmid*dx, py = oy + tmid*dy, pz = oz + tmid*dz;
        bool mask = (fabsf(px)<=1.3f) && (fabsf(py)<=1.3f) && (fabsf(pz)<=1.3f)
                  && (tmid<=tmax) && (tmax>tmin);
        float sg = mask ? fmaxf(sigmaArr[tid], 0.f) : 0.f;
        alpha = 1.0f - expf(-sg*dist);
        if (mask){
            rr = 1.0f/(1.0f+expf(-rgbArr[tid*3+0]));
            rg = 1.0f/(1.0f+expf(-rgbArr[tid*3+1]));
            rb = 1.0f/(1.0f+expf(-rgbArr[tid*3+2]));
        }
    }
    // inclusive product scan within wave (waves 0,1 hold samples)
    float p = 1.0f - alpha + 1e-10f;
    #pragma unroll
    for (int off=1; off<64; off<<=1){
        float u = __shfl_up(p, off, 64);
        if (lane >= off) p *= u;
    }
    if (tid < 128 && lane == 63) wtot[wv] = p;
    float excl = __shfl_up(p, 1, 64);
    if (lane == 0) excl = 1.0f;
    __syncthreads();
    if (tid < 128){
        float T = excl;
        if (wv == 1) T *= wtot[0];
        float w = alpha * T;
        float v0 = wred64(w*rr);
        float v1 = wred64(w*rg);
        float v2 = wred64(w*rb);
        float v3 = wred64(w);
        if (lane == 0){
            partial[wv*4+0]=v0; partial[wv*4+1]=v1; partial[wv*4+2]=v2; partial[wv*4+3]=v3;
        }
    }
    __syncthreads();
    if (tid == 0){
        float acc = partial[3] + partial[7];
        float bg  = 1.0f - acc;
        out[ray*3+0] = partial[0] + partial[4] + bg;
        out[ray*3+1] = partial[1] + partial[5] + bg;
        out[ray*3+2] = partial[2] + partial[6] + bg;
    }
}

extern "C" void kernel_launch(void* const* d_in, const int* in_sizes, int n_in,
                              void* d_out, int out_size, void* d_ws, size_t ws_size,
                              hipStream_t stream){
    const float* rays_o = (const float*)d_in[0];
    const float* rays_d = (const float*)d_in[1];
    const float* Gxy    = (const float*)d_in[2];
    const float* Gxz    = (const float*)d_in[3];
    const float* Gyz    = (const float*)d_in[4];
    const float* F_grid = (const float*)d_in[5];
    const float* sW0    = (const float*)d_in[6];
    const float* sW1    = (const float*)d_in[7];
    const float* sW2    = (const float*)d_in[8];
    const float* cW0    = (const float*)d_in[9];
    const float* cW1    = (const float*)d_in[10];
    const float* cW2    = (const float*)d_in[11];

    short* Wp = (short*)d_ws;   // 29696 shorts = 59.4 KB packed weights

    pack_all<<<(PACK_TOTAL+255)/256, 256, 0, stream>>>(sW0,sW1,sW2,cW0,cW1,cW2,Wp);
    nerf_mfma<<<2048, 256, 0, stream>>>(rays_o, rays_d, Gxy, Gxz, Gyz, F_grid, Wp, (float*)d_out);
}

// Round 3
// 182.541 us; speedup vs baseline: 3.9080x; 1.0278x over previous
//
#include <hip/hip_runtime.h>
#include <math.h>

#define RES 192
#define RANK 8
#define NI 128
#define LW 136   // padded LDS row width (shorts)

typedef __attribute__((ext_vector_type(8))) short short8;
typedef __attribute__((ext_vector_type(4))) float floatx4;

// packed-weight offsets in shorts (each fragment chunk: 64 lanes * 8 bf16)
#define OFF_SW0 0        // 8 ntiles * 1 kstep  * 512 = 4096
#define OFF_SW1 4096     // 8 * 4 * 512 = 16384
#define OFF_SW2 20480    // 1 * 4 * 512 = 2048
#define OFF_CW0 22528    // 4 * 1 * 512 = 2048
#define OFF_CW1 24576    // 4 * 2 * 512 = 4096
#define OFF_CW2 28672    // 1 * 2 * 512 = 1024
#define PACK_TOTAL 29696

__device__ __forceinline__ short f2bf(float x){
    unsigned u = __float_as_uint(x);
    unsigned r = (u + 0x7FFFu + ((u >> 16) & 1u)) >> 16;   // RTNE
    return (short)r;
}

__device__ __forceinline__ void prep_idx(float c, int size, int& i0, float& f){
    float idx = (c + 1.0f)*0.5f*(float)(size-1);
    idx = fminf(fmaxf(idx, 0.0f), (float)(size-1));
    int ii = (int)idx;               // idx >= 0, trunc == floor
    if (ii > size-2) ii = size-2;
    i0 = ii;
    f = idx - (float)ii;
}

__device__ __forceinline__ float wred64(float v){
    #pragma unroll
    for (int o=32;o>0;o>>=1) v += __shfl_down(v, o, 64);
    return v;
}

// Pack all 6 weight matrices into MFMA B-fragment order:
// chunk (ntile,kstep): 64 lanes x 8 bf16; element j of lane: W[k][n],
// k = kstep*32 + (lane>>4)*8 + j, n = ntile*16 + (lane&15); zero-pad outside.
__global__ void pack_all(const float* __restrict__ sW0, const float* __restrict__ sW1,
                         const float* __restrict__ sW2, const float* __restrict__ cW0,
                         const float* __restrict__ cW1, const float* __restrict__ cW2,
                         short* __restrict__ dst){
    int e = blockIdx.x*256 + threadIdx.x;
    if (e >= PACK_TOTAL) return;
    const float* src; int K, N, ksteps, base;
    if      (e < OFF_SW1){ src=sW0; K=32;  N=128; ksteps=1; base=OFF_SW0; }
    else if (e < OFF_SW2){ src=sW1; K=128; N=128; ksteps=4; base=OFF_SW1; }
    else if (e < OFF_CW0){ src=sW2; K=128; N=16;  ksteps=4; base=OFF_SW2; }
    else if (e < OFF_CW1){ src=cW0; K=31;  N=64;  ksteps=1; base=OFF_CW0; }
    else if (e < OFF_CW2){ src=cW1; K=64;  N=64;  ksteps=2; base=OFF_CW1; }
    else                 { src=cW2; K=64;  N=3;   ksteps=2; base=OFF_CW2; }
    int i = e - base;
    int j = i & 7, lane = (i>>3)&63, t = i>>9;
    int ks = t % ksteps, nt = t / ksteps;
    int k = ks*32 + (lane>>4)*8 + j;
    int n = nt*16 + (lane&15);
    float v = (k < K && n < N) ? src[k*N + n] : 0.0f;
    dst[e] = f2bf(v);
}

// --------- kernel A: per-sample gather + trilinear interp -> Fv (bf16) ---------
// thread = sample; no LDS, no barriers; masked samples write zeros (zero input
// through the bias-free MLP reproduces the reference's masked sigma=0 exactly).
__global__ void __launch_bounds__(256) interp_kernel(
    const float* __restrict__ rays_o, const float* __restrict__ rays_d,
    const float* __restrict__ Gxy, const float* __restrict__ Gxz, const float* __restrict__ Gyz,
    const float* __restrict__ F_grid, short* __restrict__ FvOut)
{
    const int g   = blockIdx.x*256 + threadIdx.x;   // 262144 threads
    const int ray = g >> 7;
    const int s   = g & 127;

    const float ox = rays_o[ray*3+0], oy = rays_o[ray*3+1], oz = rays_o[ray*3+2];
    const float dx = rays_d[ray*3+0], dy = rays_d[ray*3+1], dz = rays_d[ray*3+2];

    float sdx = (fabsf(dx) < 1e-9f) ? 1e-9f : dx;
    float sdy = (fabsf(dy) < 1e-9f) ? 1e-9f : dy;
    float sdz = (fabsf(dz) < 1e-9f) ? 1e-9f : dz;
    float t1x = (-1.3f - ox)/sdx, t2x = (1.3f - ox)/sdx;
    float t1y = (-1.3f - oy)/sdy, t2y = (1.3f - oy)/sdy;
    float t1z = (-1.3f - oz)/sdz, t2z = (1.3f - oz)/sdz;
    float tmin = fmaxf(fminf(t1x,t2x), fmaxf(fminf(t1y,t2y), fminf(t1z,t2z)));
    float tmax = fminf(fmaxf(t1x,t2x), fminf(fmaxf(t1y,t2y), fmaxf(t1z,t2z)));
    float nearv = fmaxf(tmin, 0.0f);

    float ts0 = nearv + (float)s     * 0.0352f;
    float ts1 = nearv + (float)(s+1) * 0.0352f;
    float tmid = 0.5f*(ts0+ts1);
    float px = ox + tmid*dx, py = oy + tmid*dy, pz = oz + tmid*dz;
    bool mask = (fabsf(px)<=1.3f) && (fabsf(py)<=1.3f) && (fabsf(pz)<=1.3f)
              && (tmid<=tmax) && (tmax>tmin);

    short8 rOut[4];
    #pragma unroll
    for (int q=0;q<4;q++){
        #pragma unroll
        for (int j=0;j<8;j++) rOut[q][j] = 0;
    }

    if (mask){
        float p0 = (px/1.3f + 1.0f)*192.0f/2.0f*2.0f/192.0f - 1.0f;
        float p1 = (py/1.3f + 1.0f)*192.0f/2.0f*2.0f/192.0f - 1.0f;
        float p2 = (pz/1.3f + 1.0f)*192.0f/2.0f*2.0f/192.0f - 1.0f;

        int x0, y0, z0; float fx, fy, fz;
        prep_idx(p0, RES, x0, fx);
        prep_idx(p1, RES, y0, fy);
        prep_idx(p2, RES, z0, fz);

        float gv0=0.f, gv1=0.f, gv2=0.f;
        #pragma unroll
        for (int zc=0; zc<2; zc++){
            const int zi = z0 + zc;
            const float wz = zc ? fz : (1.0f - fz);
            #pragma unroll
            for (int yc=0; yc<2; yc++){
                const int yi = y0 + yc;
                const float wy = yc ? fy : (1.0f - fy);
                const float* __restrict__ pxy = Gxy + (size_t)((zi*RES + yi)*3)*RANK;
                const float wzy = wz*wy;
                #pragma unroll
                for (int xc=0; xc<2; xc++){
                    const int xi = x0 + xc;
                    const float wx = xc ? fx : (1.0f - fx);
                    const float* __restrict__ pxz = Gxz + (size_t)((zi*RES + xi)*3)*RANK;
                    const float* __restrict__ pyz = Gyz + (size_t)((yi*RES + xi)*3)*RANK;
                    const float w = wzy*wx;
                    float s0=0.f,s1=0.f,s2=0.f;
                    #pragma unroll
                    for (int r=0;r<RANK;r++){
                        s0 = fmaf(pxy[r]    *pxz[r],    pyz[r],    s0);
                        s1 = fmaf(pxy[8+r]  *pxz[8+r],  pyz[8+r],  s1);
                        s2 = fmaf(pxy[16+r] *pxz[16+r], pyz[16+r], s2);
                    }
                    gv0 = fmaf(w, s0, gv0);
                    gv1 = fmaf(w, s1, gv1);
                    gv2 = fmaf(w, s2, gv2);
                }
            }
        }

        int a0,b0,c0; float fa,fb,fc;
        prep_idx(gv2, 32, a0, fa);
        prep_idx(gv1, 32, b0, fb);
        prep_idx(gv0, 32, c0, fc);
        float Fv[32];
        #pragma unroll
        for (int k=0;k<32;k++) Fv[k]=0.f;
        #pragma unroll
        for (int zc=0; zc<2; zc++){
            const int zi = a0+zc; const float wz = zc ? fa : 1.f-fa;
            #pragma unroll
            for (int yc=0; yc<2; yc++){
                const int yi = b0+yc; const float wy = yc ? fb : 1.f-fb;
                #pragma unroll
                for (int xc=0; xc<2; xc++){
                    const int xi = c0+xc; const float wx = xc ? fc : 1.f-fc;
                    const float w = wz*wy*wx;
                    const float* __restrict__ pf = F_grid + (size_t)(((zi*32)+yi)*32+xi)*32;
                    #pragma unroll
                    for (int k=0;k<32;k++) Fv[k] = fmaf(w, pf[k], Fv[k]);
                }
            }
        }
        #pragma unroll
        for (int q=0;q<4;q++){
            #pragma unroll
            for (int j=0;j<8;j++) rOut[q][j] = f2bf(Fv[q*8+j]);
        }
    }

    short8* dst = (short8*)(FvOut + (size_t)g*32);
    dst[0]=rOut[0]; dst[1]=rOut[1]; dst[2]=rOut[2]; dst[3]=rOut[3];
}

// --------- kernel B: MFMA MLPs + compositing (block = ray) ---------
__launch_bounds__(256, 2)
__global__ void nerf_mlp(
    const float* __restrict__ rays_o, const float* __restrict__ rays_d,
    const short* __restrict__ Wp, const short* __restrict__ Fv,
    float* __restrict__ out)
{
    __shared__ short buf[128*LW];        // activations; rows are WAVE-PRIVATE
    __shared__ float sigmaArr[128];
    __shared__ float rgbArr[128*3];
    __shared__ float wtot[2];
    __shared__ float partial[8];

    const int tid  = threadIdx.x;
    const int lane = tid & 63;
    const int wv   = tid >> 6;           // wave 0..3
    const int ray  = blockIdx.x;

    const float ox = rays_o[ray*3+0], oy = rays_o[ray*3+1], oz = rays_o[ray*3+2];
    const float dx = rays_d[ray*3+0], dy = rays_d[ray*3+1], dz = rays_d[ray*3+2];

    float sdx = (fabsf(dx) < 1e-9f) ? 1e-9f : dx;
    float sdy = (fabsf(dy) < 1e-9f) ? 1e-9f : dy;
    float sdz = (fabsf(dz) < 1e-9f) ? 1e-9f : dz;
    float t1x = (-1.3f - ox)/sdx, t2x = (1.3f - ox)/sdx;
    float t1y = (-1.3f - oy)/sdy, t2y = (1.3f - oy)/sdy;
    float t1z = (-1.3f - oz)/sdz, t2z = (1.3f - oz)/sdz;
    float tmin = fmaxf(fminf(t1x,t2x), fmaxf(fminf(t1y,t2y), fminf(t1z,t2z)));
    float tmax = fminf(fmaxf(t1x,t2x), fminf(fmaxf(t1y,t2y), fmaxf(t1z,t2z)));
    float nearv = fmaxf(tmin, 0.0f);

    const int rowbase = wv*32;
    const int col  = lane & 15;
    const int quad = lane >> 4;
    const int ar0  = rowbase + col;        // A row, mtile 0
    const int ar1  = ar0 + 16;             // A row, mtile 1

    // L1: 32 -> 128, relu. A-frags straight from global (coalesced 1KB/wave).
    {
        const short8* FvG = (const short8*)(Fv + (size_t)ray*128*32);
        short8 a0 = FvG[ar0*4 + quad];
        short8 a1 = FvG[ar1*4 + quad];
        const short8* W = (const short8*)(Wp + OFF_SW0);
        #pragma unroll
        for (int nt=0; nt<8; nt++){
            short8 b = W[nt*64 + lane];
            floatx4 c0v = {0.f,0.f,0.f,0.f}, c1v = {0.f,0.f,0.f,0.f};
            c0v = __builtin_amdgcn_mfma_f32_16x16x32_bf16(a0, b, c0v, 0,0,0);
            c1v = __builtin_amdgcn_mfma_f32_16x16x32_bf16(a1, b, c1v, 0,0,0);
            #pragma unroll
            for (int r=0;r<4;r++){
                int row0 = rowbase + quad*4 + r;
                buf[row0*LW      + nt*16 + col] = f2bf(fmaxf(c0v[r],0.f));
                buf[(row0+16)*LW + nt*16 + col] = f2bf(fmaxf(c1v[r],0.f));
            }
        }
    }
    // no barrier: rows are wave-private

    // L2: 128 -> 128, relu
    {
        short8 A0[4], A1[4];
        #pragma unroll
        for (int ks=0;ks<4;ks++){
            A0[ks] = *(const short8*)&buf[ar0*LW + ks*32 + quad*8];
            A1[ks] = *(const short8*)&buf[ar1*LW + ks*32 + quad*8];
        }
        const short8* W = (const short8*)(Wp + OFF_SW1);
        #pragma unroll
        for (int nt=0; nt<8; nt++){
            floatx4 c0v = {0.f,0.f,0.f,0.f}, c1v = {0.f,0.f,0.f,0.f};
            #pragma unroll
            for (int ks=0;ks<4;ks++){
                short8 b = W[(nt*4+ks)*64 + lane];
                c0v = __builtin_amdgcn_mfma_f32_16x16x32_bf16(A0[ks], b, c0v, 0,0,0);
                c1v = __builtin_amdgcn_mfma_f32_16x16x32_bf16(A1[ks], b, c1v, 0,0,0);
            }
            #pragma unroll
            for (int r=0;r<4;r++){
                int row0 = rowbase + quad*4 + r;
                buf[row0*LW      + nt*16 + col] = f2bf(fmaxf(c0v[r],0.f));
                buf[(row0+16)*LW + nt*16 + col] = f2bf(fmaxf(c1v[r],0.f));
            }
        }
    }

    // L3: 128 -> 16 (no relu). col0 -> sigmaArr, cols 1..15 -> buf cols 16..30.
    {
        short8 A0[4], A1[4];
        #pragma unroll
        for (int ks=0;ks<4;ks++){
            A0[ks] = *(const short8*)&buf[ar0*LW + ks*32 + quad*8];
            A1[ks] = *(const short8*)&buf[ar1*LW + ks*32 + quad*8];
        }
        const short8* W = (const short8*)(Wp + OFF_SW2);
        floatx4 c0v = {0.f,0.f,0.f,0.f}, c1v = {0.f,0.f,0.f,0.f};
        #pragma unroll
        for (int ks=0;ks<4;ks++){
            short8 b = W[ks*64 + lane];
            c0v = __builtin_amdgcn_mfma_f32_16x16x32_bf16(A0[ks], b, c0v, 0,0,0);
            c1v = __builtin_amdgcn_mfma_f32_16x16x32_bf16(A1[ks], b, c1v, 0,0,0);
        }
        #pragma unroll
        for (int r=0;r<4;r++){
            int row0 = rowbase + quad*4 + r;
            if (col == 0){
                sigmaArr[row0]    = c0v[r];
                sigmaArr[row0+16] = c1v[r];
            } else {
                buf[row0*LW      + 15 + col] = f2bf(c0v[r]);
                buf[(row0+16)*LW + 15 + col] = f2bf(c1v[r]);
            }
        }
        // SH basis (ray-uniform) -> cols 0..15 of this wave's rows
        const float dn = sqrtf(dx*dx+dy*dy+dz*dz);
        const float X = dx/dn, Y = dy/dn, Z = dz/dn;
        const float X2=X*X, Y2=Y*Y, Z2=Z*Z;
        float sh[16];
        sh[0]= 0.28209479177387814f;
        sh[1]=-0.48860251190291987f*Y;
        sh[2]= 0.48860251190291987f*Z;
        sh[3]=-0.48860251190291987f*X;
        sh[4]= 1.0925484305920792f*X*Y;
        sh[5]=-1.0925484305920792f*Y*Z;
        sh[6]= 0.94617469575756f*Z2 - 0.31539156525252f;
        sh[7]=-1.0925484305920792f*X*Z;
        sh[8]= 0.5462742152960396f*(X2-Y2);
        sh[9]= 0.5900435899266435f*Y*(-3.0f*X2+Y2);
        sh[10]=2.890611442640554f*X*Y*Z;
        sh[11]=0.4570457994644657f*Y*(1.0f-5.0f*Z2);
        sh[12]=0.3731763325901154f*Z*(5.0f*Z2-3.0f);
        sh[13]=0.4570457994644657f*X*(1.0f-5.0f*Z2);
        sh[14]=1.445305721320277f*Z*(X2-Y2);
        sh[15]=0.5900435899266435f*X*(-X2+3.0f*Y2);
        if (lane < 32){
            int row = rowbase + lane;
            #pragma unroll
            for (int k=0;k<16;k++) buf[row*LW + k] = f2bf(sh[k]);
        }
    }

    // CL1: 31(pad32) -> 64, relu
    {
        short8 a0 = *(const short8*)&buf[ar0*LW + quad*8];
        short8 a1 = *(const short8*)&buf[ar1*LW + quad*8];
        const short8* W = (const short8*)(Wp + OFF_CW0);
        #pragma unroll
        for (int nt=0; nt<4; nt++){
            short8 b = W[nt*64 + lane];
            floatx4 c0v = {0.f,0.f,0.f,0.f}, c1v = {0.f,0.f,0.f,0.f};
            c0v = __builtin_amdgcn_mfma_f32_16x16x32_bf16(a0, b, c0v, 0,0,0);
            c1v = __builtin_amdgcn_mfma_f32_16x16x32_bf16(a1, b, c1v, 0,0,0);
            #pragma unroll
            for (int r=0;r<4;r++){
                int row0 = rowbase + quad*4 + r;
                buf[row0*LW      + nt*16 + col] = f2bf(fmaxf(c0v[r],0.f));
                buf[(row0+16)*LW + nt*16 + col] = f2bf(fmaxf(c1v[r],0.f));
            }
        }
    }

    // CL2: 64 -> 64, relu
    {
        short8 A0[2], A1[2];
        #pragma unroll
        for (int ks=0;ks<2;ks++){
            A0[ks] = *(const short8*)&buf[ar0*LW + ks*32 + quad*8];
            A1[ks] = *(const short8*)&buf[ar1*LW + ks*32 + quad*8];
        }
        const short8* W = (const short8*)(Wp + OFF_CW1);
        #pragma unroll
        for (int nt=0; nt<4; nt++){
            floatx4 c0v = {0.f,0.f,0.f,0.f}, c1v = {0.f,0.f,0.f,0.f};
            #pragma unroll
            for (int ks=0;ks<2;ks++){
                short8 b = W[(nt*2+ks)*64 + lane];
                c0v = __builtin_amdgcn_mfma_f32_16x16x32_bf16(A0[ks], b, c0v, 0,0,0);
                c1v = __builtin_amdgcn_mfma_f32_16x16x32_bf16(A1[ks], b, c1v, 0,0,0);
            }
            #pragma unroll
            for (int r=0;r<4;r++){
                int row0 = rowbase + quad*4 + r;
                buf[row0*LW      + nt*16 + col] = f2bf(fmaxf(c0v[r],0.f));
                buf[(row0+16)*LW + nt*16 + col] = f2bf(fmaxf(c1v[r],0.f));
            }
        }
    }

    // CL3: 64 -> 3, no relu -> rgbArr
    {
        short8 A0[2], A1[2];
        #pragma unroll
        for (int ks=0;ks<2;ks++){
            A0[ks] = *(const short8*)&buf[ar0*LW + ks*32 + quad*8];
            A1[ks] = *(const short8*)&buf[ar1*LW + ks*32 + quad*8];
        }
        const short8* W = (const short8*)(Wp + OFF_CW2);
        floatx4 c0v = {0.f,0.f,0.f,0.f}, c1v = {0.f,0.f,0.f,0.f};
        #pragma unroll
        for (int ks=0;ks<2;ks++){
            short8 b = W[ks*64 + lane];
            c0v = __builtin_amdgcn_mfma_f32_16x16x32_bf16(A0[ks], b, c0v, 0,0,0);
            c1v = __builtin_amdgcn_mfma_f32_16x16x32_bf16(A1[ks], b, c1v, 0,0,0);
        }
        if (col < 3){
            #pragma unroll
            for (int r=0;r<4;r++){
                int row0 = rowbase + quad*4 + r;
                rgbArr[row0*3 + col]      = c0v[r];
                rgbArr[(row0+16)*3 + col] = c1v[r];
            }
        }
    }
    __syncthreads();   // the one cross-wave handoff: sigmaArr/rgbArr -> waves 0,1

    // ---------------- compositing (threads 0..127, sample = tid) ----------------
    float alpha = 0.f, rr = 0.f, rg = 0.f, rb = 0.f;
    if (tid < 128){
        float ts0 = nearv + (float)tid     * 0.0352f;
        float ts1 = nearv + (float)(tid+1) * 0.0352f;
        float tmid = 0.5f*(ts0+ts1);
        float dist = ts1 - ts0;
        float px = ox + tmid*dx, py = oy + tmid*dy, pz = oz + tmid*dz;
        bool mask = (fabsf(px)<=1.3f) && (fabsf(py)<=1.3f) && (fabsf(pz)<=1.3f)
                  && (tmid<=tmax) && (tmax>tmin);
        float sg = mask ? fmaxf(sigmaArr[tid], 0.f) : 0.f;
        alpha = 1.0f - expf(-sg*dist);
        if (mask){
            rr = 1.0f/(1.0f+expf(-rgbArr[tid*3+0]));
            rg = 1.0f/(1.0f+expf(-rgbArr[tid*3+1]));
            rb = 1.0f/(1.0f+expf(-rgbArr[tid*3+2]));
        }
    }
    float p = 1.0f - alpha + 1e-10f;
    #pragma unroll
    for (int off=1; off<64; off<<=1){
        float u = __shfl_up(p, off, 64);
        if (lane >= off) p *= u;
    }
    if (tid < 128 && lane == 63) wtot[wv] = p;
    float excl = __shfl_up(p, 1, 64);
    if (lane == 0) excl = 1.0f;
    __syncthreads();
    if (tid < 128){
        float T = excl;
        if (wv == 1) T *= wtot[0];
        float w = alpha * T;
        float v0 = wred64(w*rr);
        float v1 = wred64(w*rg);
        float v2 = wred64(w*rb);
        float v3 = wred64(w);
        if (lane == 0){
            partial[wv*4+0]=v0; partial[wv*4+1]=v1; partial[wv*4+2]=v2; partial[wv*4+3]=v3;
        }
    }
    __syncthreads();
    if (tid == 0){
        float acc = partial[3] + partial[7];
        float bg  = 1.0f - acc;
        out[ray*3+0] = partial[0] + partial[4] + bg;
        out[ray*3+1] = partial[1] + partial[5] + bg;
        out[ray*3+2] = partial[2] + partial[6] + bg;
    }
}

extern "C" void kernel_launch(void* const* d_in, const int* in_sizes, int n_in,
                              void* d_out, int out_size, void* d_ws, size_t ws_size,
                              hipStream_t stream){
    const float* rays_o = (const float*)d_in[0];
    const float* rays_d = (const float*)d_in[1];
    const float* Gxy    = (const float*)d_in[2];
    const float* Gxz    = (const float*)d_in[3];
    const float* Gyz    = (const float*)d_in[4];
    const float* F_grid = (const float*)d_in[5];
    const float* sW0    = (const float*)d_in[6];
    const float* sW1    = (const float*)d_in[7];
    const float* sW2    = (const float*)d_in[8];
    const float* cW0    = (const float*)d_in[9];
    const float* cW1    = (const float*)d_in[10];
    const float* cW2    = (const float*)d_in[11];

    short* Wp   = (short*)d_ws;                       // 59392 B packed weights
    short* FvWS = (short*)d_ws + PACK_TOTAL;          // 2048*128*32 bf16 = 16.78 MB

    pack_all<<<(PACK_TOTAL+255)/256, 256, 0, stream>>>(sW0,sW1,sW2,cW0,cW1,cW2,Wp);
    interp_kernel<<<1024, 256, 0, stream>>>(rays_o, rays_d, Gxy, Gxz, Gyz, F_grid, FvWS);
    nerf_mlp<<<2048, 256, 0, stream>>>(rays_o, rays_d, Wp, FvWS, (float*)d_out);
}

// Round 4
// 148.954 us; speedup vs baseline: 4.7891x; 1.2255x over previous
//
#include <hip/hip_runtime.h>
#include <math.h>

#define RES 192
#define RANK 8
#define NI 128
#define LW 136   // padded LDS row width (shorts)

typedef __attribute__((ext_vector_type(8))) short short8;
typedef __attribute__((ext_vector_type(4))) float floatx4;

// packed-weight offsets in shorts (each fragment chunk: 64 lanes * 8 bf16)
#define OFF_SW0 0        // 8 ntiles * 1 kstep  * 512 = 4096
#define OFF_SW1 4096     // 8 * 4 * 512 = 16384
#define OFF_SW2 20480    // 1 * 4 * 512 = 2048
#define OFF_CW0 22528    // 4 * 1 * 512 = 2048
#define OFF_CW1 24576    // 4 * 2 * 512 = 4096
#define OFF_CW2 28672    // 1 * 2 * 512 = 1024
#define PACK_TOTAL 29696

#define TRI_CELLS (RES*RES)          // 36864 cells per plane
#define TRI_TOTAL (3*TRI_CELLS*24)   // elements to convert
#define FG_TOTAL  (32*32*32*32)      // 1048576

__device__ __forceinline__ short f2bf(float x){
    unsigned u = __float_as_uint(x);
    unsigned r = (u + 0x7FFFu + ((u >> 16) & 1u)) >> 16;   // RTNE
    return (short)r;
}
__device__ __forceinline__ float bf2f(short s){
    return __uint_as_float(((unsigned)(unsigned short)s) << 16);
}

__device__ __forceinline__ void prep_idx(float c, int size, int& i0, float& f){
    float idx = (c + 1.0f)*0.5f*(float)(size-1);
    idx = fminf(fmaxf(idx, 0.0f), (float)(size-1));
    int ii = (int)idx;               // idx >= 0, trunc == floor
    if (ii > size-2) ii = size-2;
    i0 = ii;
    f = idx - (float)ii;
}

__device__ __forceinline__ float wred64(float v){
    #pragma unroll
    for (int o=32;o>0;o>>=1) v += __shfl_down(v, o, 64);
    return v;
}

// Pack all 6 weight matrices into MFMA B-fragment order.
__global__ void pack_all(const float* __restrict__ sW0, const float* __restrict__ sW1,
                         const float* __restrict__ sW2, const float* __restrict__ cW0,
                         const float* __restrict__ cW1, const float* __restrict__ cW2,
                         short* __restrict__ dst){
    int e = blockIdx.x*256 + threadIdx.x;
    if (e >= PACK_TOTAL) return;
    const float* src; int K, N, ksteps, base;
    if      (e < OFF_SW1){ src=sW0; K=32;  N=128; ksteps=1; base=OFF_SW0; }
    else if (e < OFF_SW2){ src=sW1; K=128; N=128; ksteps=4; base=OFF_SW1; }
    else if (e < OFF_CW0){ src=sW2; K=128; N=16;  ksteps=4; base=OFF_SW2; }
    else if (e < OFF_CW1){ src=cW0; K=31;  N=64;  ksteps=1; base=OFF_CW0; }
    else if (e < OFF_CW2){ src=cW1; K=64;  N=64;  ksteps=2; base=OFF_CW1; }
    else                 { src=cW2; K=64;  N=3;   ksteps=2; base=OFF_CW2; }
    int i = e - base;
    int j = i & 7, lane = (i>>3)&63, t = i>>9;
    int ks = t % ksteps, nt = t / ksteps;
    int k = ks*32 + (lane>>4)*8 + j;
    int n = nt*16 + (lane&15);
    float v = (k < K && n < N) ? src[k*N + n] : 0.0f;
    dst[e] = f2bf(v);
}

// bf16-ify triplanes into padded cells: dst[(plane*36864 + cell)*32 + c], c<24
__global__ void conv_tri(const float* __restrict__ Gxy, const float* __restrict__ Gxz,
                         const float* __restrict__ Gyz, short* __restrict__ dst){
    int e = blockIdx.x*256 + threadIdx.x;
    if (e >= TRI_TOTAL) return;
    int p    = e / (TRI_CELLS*24);
    int rem  = e - p*(TRI_CELLS*24);
    int cell = rem / 24;
    int c    = rem - cell*24;
    const float* src = (p==0) ? Gxy : (p==1) ? Gxz : Gyz;
    dst[((size_t)(p*TRI_CELLS + cell))*32 + c] = f2bf(src[(size_t)cell*24 + c]);
}

// bf16-ify F_grid (layout already [cell][32] contiguous)
__global__ void conv_fg(const float* __restrict__ F_grid, short* __restrict__ dst){
    int e = blockIdx.x*256 + threadIdx.x;
    if (e >= FG_TOTAL) return;
    dst[e] = f2bf(F_grid[e]);
}

// --------- kernel A: 2 threads per sample, bf16 tables ---------
// block = ray (256 threads); sample = tid>>1, half = tid&1.
// Half h: triplane corners zc=h (gv combined via shfl_xor), F-grid channels [16h,16h+16).
__global__ void __launch_bounds__(256) interp2(
    const float* __restrict__ rays_o, const float* __restrict__ rays_d,
    const short* __restrict__ Gp, const short* __restrict__ Fg,
    short* __restrict__ FvOut)
{
    const int tid = threadIdx.x;
    const int ray = blockIdx.x;
    const int s   = tid >> 1;
    const int h   = tid & 1;

    const float ox = rays_o[ray*3+0], oy = rays_o[ray*3+1], oz = rays_o[ray*3+2];
    const float dx = rays_d[ray*3+0], dy = rays_d[ray*3+1], dz = rays_d[ray*3+2];

    float sdx = (fabsf(dx) < 1e-9f) ? 1e-9f : dx;
    float sdy = (fabsf(dy) < 1e-9f) ? 1e-9f : dy;
    float sdz = (fabsf(dz) < 1e-9f) ? 1e-9f : dz;
    float t1x = (-1.3f - ox)/sdx, t2x = (1.3f - ox)/sdx;
    float t1y = (-1.3f - oy)/sdy, t2y = (1.3f - oy)/sdy;
    float t1z = (-1.3f - oz)/sdz, t2z = (1.3f - oz)/sdz;
    float tmin = fmaxf(fminf(t1x,t2x), fmaxf(fminf(t1y,t2y), fminf(t1z,t2z)));
    float tmax = fminf(fmaxf(t1x,t2x), fminf(fmaxf(t1y,t2y), fmaxf(t1z,t2z)));
    float nearv = fmaxf(tmin, 0.0f);

    float ts0 = nearv + (float)s     * 0.0352f;
    float ts1 = nearv + (float)(s+1) * 0.0352f;
    float tmid = 0.5f*(ts0+ts1);
    float px = ox + tmid*dx, py = oy + tmid*dy, pz = oz + tmid*dz;
    bool mask = (fabsf(px)<=1.3f) && (fabsf(py)<=1.3f) && (fabsf(pz)<=1.3f)
              && (tmid<=tmax) && (tmax>tmin);

    short8 o0 = {0,0,0,0,0,0,0,0};
    short8 o1 = {0,0,0,0,0,0,0,0};

    if (mask){
        float p0 = (px/1.3f + 1.0f)*192.0f/2.0f*2.0f/192.0f - 1.0f;
        float p1 = (py/1.3f + 1.0f)*192.0f/2.0f*2.0f/192.0f - 1.0f;
        float p2 = (pz/1.3f + 1.0f)*192.0f/2.0f*2.0f/192.0f - 1.0f;

        int x0, y0, z0; float fx, fy, fz;
        prep_idx(p0, RES, x0, fx);
        prep_idx(p1, RES, y0, fy);
        prep_idx(p2, RES, z0, fz);

        // ---- triplane: this half handles zc = h (one cache line per cell) ----
        const int zi = z0 + h;
        const float wzc = h ? fz : (1.0f - fz);

        short8 XY[2][3], XZ[2][3], YZ[2][2][3];
        {
            const short8* pxy0 = (const short8*)(Gp + ((size_t)(zi*RES + y0  ))*32);
            const short8* pxy1 = (const short8*)(Gp + ((size_t)(zi*RES + y0+1))*32);
            const short8* pxz0 = (const short8*)(Gp + ((size_t)(TRI_CELLS + zi*RES + x0  ))*32);
            const short8* pxz1 = (const short8*)(Gp + ((size_t)(TRI_CELLS + zi*RES + x0+1))*32);
            const short8* pyz00 = (const short8*)(Gp + ((size_t)(2*TRI_CELLS + (y0  )*RES + x0  ))*32);
            const short8* pyz01 = (const short8*)(Gp + ((size_t)(2*TRI_CELLS + (y0  )*RES + x0+1))*32);
            const short8* pyz10 = (const short8*)(Gp + ((size_t)(2*TRI_CELLS + (y0+1)*RES + x0  ))*32);
            const short8* pyz11 = (const short8*)(Gp + ((size_t)(2*TRI_CELLS + (y0+1)*RES + x0+1))*32);
            #pragma unroll
            for (int q=0;q<3;q++){
                XY[0][q]=pxy0[q]; XY[1][q]=pxy1[q];
                XZ[0][q]=pxz0[q]; XZ[1][q]=pxz1[q];
                YZ[0][0][q]=pyz00[q]; YZ[0][1][q]=pyz01[q];
                YZ[1][0][q]=pyz10[q]; YZ[1][1][q]=pyz11[q];
            }
        }

        float gv0=0.f, gv1=0.f, gv2=0.f;
        #pragma unroll
        for (int yc=0; yc<2; yc++){
            const float wy = yc ? fy : (1.0f - fy);
            #pragma unroll
            for (int xc=0; xc<2; xc++){
                const float wx = xc ? fx : (1.0f - fx);
                const float w = wzc*wy*wx;
                float s0=0.f, s1=0.f, s2=0.f;
                #pragma unroll
                for (int r=0;r<8;r++){
                    s0 = fmaf(bf2f(XY[yc][0][r])*bf2f(XZ[xc][0][r]), bf2f(YZ[yc][xc][0][r]), s0);
                    s1 = fmaf(bf2f(XY[yc][1][r])*bf2f(XZ[xc][1][r]), bf2f(YZ[yc][xc][1][r]), s1);
                    s2 = fmaf(bf2f(XY[yc][2][r])*bf2f(XZ[xc][2][r]), bf2f(YZ[yc][xc][2][r]), s2);
                }
                gv0 = fmaf(w, s0, gv0);
                gv1 = fmaf(w, s1, gv1);
                gv2 = fmaf(w, s2, gv2);
            }
        }
        // combine the two zc halves (pair lanes have identical mask)
        gv0 += __shfl_xor(gv0, 1, 64);
        gv1 += __shfl_xor(gv1, 1, 64);
        gv2 += __shfl_xor(gv2, 1, 64);

        // ---- F-grid: this half computes channels [16h, 16h+16) of all 8 corners ----
        int a0,b0,c0; float fa,fb,fc;
        prep_idx(gv2, 32, a0, fa);
        prep_idx(gv1, 32, b0, fb);
        prep_idx(gv0, 32, c0, fc);
        float Fv[16];
        #pragma unroll
        for (int k=0;k<16;k++) Fv[k]=0.f;
        #pragma unroll
        for (int zc=0; zc<2; zc++){
            const int zi2 = a0+zc; const float wz2 = zc ? fa : 1.f-fa;
            #pragma unroll
            for (int yc=0; yc<2; yc++){
                const int yi2 = b0+yc; const float wy2 = yc ? fb : 1.f-fb;
                #pragma unroll
                for (int xc=0; xc<2; xc++){
                    const int xi2 = c0+xc; const float wx2 = xc ? fc : 1.f-fc;
                    const float w = wz2*wy2*wx2;
                    const short8* pf = (const short8*)(Fg + ((size_t)((zi2*32+yi2)*32+xi2))*32 + h*16);
                    short8 v0 = pf[0], v1 = pf[1];
                    #pragma unroll
                    for (int j=0;j<8;j++){
                        Fv[j]   = fmaf(w, bf2f(v0[j]), Fv[j]);
                        Fv[8+j] = fmaf(w, bf2f(v1[j]), Fv[8+j]);
                    }
                }
            }
        }
        #pragma unroll
        for (int j=0;j<8;j++){ o0[j] = f2bf(Fv[j]); o1[j] = f2bf(Fv[8+j]); }
    }

    short* dstp = FvOut + (((size_t)ray*128 + s)*32 + h*16);
    *(short8*)dstp       = o0;
    *(short8*)(dstp + 8) = o1;
}

// --------- kernel B: MFMA MLPs + compositing (block = ray) ---------
__launch_bounds__(256, 2)
__global__ void nerf_mlp(
    const float* __restrict__ rays_o, const float* __restrict__ rays_d,
    const short* __restrict__ Wp, const short* __restrict__ Fv,
    float* __restrict__ out)
{
    __shared__ short buf[128*LW];        // activations; rows are WAVE-PRIVATE
    __shared__ float sigmaArr[128];
    __shared__ float rgbArr[128*3];
    __shared__ float wtot[2];
    __shared__ float partial[8];

    const int tid  = threadIdx.x;
    const int lane = tid & 63;
    const int wv   = tid >> 6;           // wave 0..3
    const int ray  = blockIdx.x;

    const float ox = rays_o[ray*3+0], oy = rays_o[ray*3+1], oz = rays_o[ray*3+2];
    const float dx = rays_d[ray*3+0], dy = rays_d[ray*3+1], dz = rays_d[ray*3+2];

    float sdx = (fabsf(dx) < 1e-9f) ? 1e-9f : dx;
    float sdy = (fabsf(dy) < 1e-9f) ? 1e-9f : dy;
    float sdz = (fabsf(dz) < 1e-9f) ? 1e-9f : dz;
    float t1x = (-1.3f - ox)/sdx, t2x = (1.3f - ox)/sdx;
    float t1y = (-1.3f - oy)/sdy, t2y = (1.3f - oy)/sdy;
    float t1z = (-1.3f - oz)/sdz, t2z = (1.3f - oz)/sdz;
    float tmin = fmaxf(fminf(t1x,t2x), fmaxf(fminf(t1y,t2y), fminf(t1z,t2z)));
    float tmax = fminf(fmaxf(t1x,t2x), fminf(fmaxf(t1y,t2y), fmaxf(t1z,t2z)));
    float nearv = fmaxf(tmin, 0.0f);

    const int rowbase = wv*32;
    const int col  = lane & 15;
    const int quad = lane >> 4;
    const int ar0  = rowbase + col;        // A row, mtile 0
    const int ar1  = ar0 + 16;             // A row, mtile 1

    // L1: 32 -> 128, relu. A-frags straight from global (coalesced 1KB/wave).
    {
        const short8* FvG = (const short8*)(Fv + (size_t)ray*128*32);
        short8 a0 = FvG[ar0*4 + quad];
        short8 a1 = FvG[ar1*4 + quad];
        const short8* W = (const short8*)(Wp + OFF_SW0);
        #pragma unroll
        for (int nt=0; nt<8; nt++){
            short8 b = W[nt*64 + lane];
            floatx4 c0v = {0.f,0.f,0.f,0.f}, c1v = {0.f,0.f,0.f,0.f};
            c0v = __builtin_amdgcn_mfma_f32_16x16x32_bf16(a0, b, c0v, 0,0,0);
            c1v = __builtin_amdgcn_mfma_f32_16x16x32_bf16(a1, b, c1v, 0,0,0);
            #pragma unroll
            for (int r=0;r<4;r++){
                int row0 = rowbase + quad*4 + r;
                buf[row0*LW      + nt*16 + col] = f2bf(fmaxf(c0v[r],0.f));
                buf[(row0+16)*LW + nt*16 + col] = f2bf(fmaxf(c1v[r],0.f));
            }
        }
    }
    // no barrier: rows are wave-private

    // L2: 128 -> 128, relu
    {
        short8 A0[4], A1[4];
        #pragma unroll
        for (int ks=0;ks<4;ks++){
            A0[ks] = *(const short8*)&buf[ar0*LW + ks*32 + quad*8];
            A1[ks] = *(const short8*)&buf[ar1*LW + ks*32 + quad*8];
        }
        const short8* W = (const short8*)(Wp + OFF_SW1);
        #pragma unroll
        for (int nt=0; nt<8; nt++){
            floatx4 c0v = {0.f,0.f,0.f,0.f}, c1v = {0.f,0.f,0.f,0.f};
            #pragma unroll
            for (int ks=0;ks<4;ks++){
                short8 b = W[(nt*4+ks)*64 + lane];
                c0v = __builtin_amdgcn_mfma_f32_16x16x32_bf16(A0[ks], b, c0v, 0,0,0);
                c1v = __builtin_amdgcn_mfma_f32_16x16x32_bf16(A1[ks], b, c1v, 0,0,0);
            }
            #pragma unroll
            for (int r=0;r<4;r++){
                int row0 = rowbase + quad*4 + r;
                buf[row0*LW      + nt*16 + col] = f2bf(fmaxf(c0v[r],0.f));
                buf[(row0+16)*LW + nt*16 + col] = f2bf(fmaxf(c1v[r],0.f));
            }
        }
    }

    // L3: 128 -> 16 (no relu). col0 -> sigmaArr, cols 1..15 -> buf cols 16..30.
    {
        short8 A0[4], A1[4];
        #pragma unroll
        for (int ks=0;ks<4;ks++){
            A0[ks] = *(const short8*)&buf[ar0*LW + ks*32 + quad*8];
            A1[ks] = *(const short8*)&buf[ar1*LW + ks*32 + quad*8];
        }
        const short8* W = (const short8*)(Wp + OFF_SW2);
        floatx4 c0v = {0.f,0.f,0.f,0.f}, c1v = {0.f,0.f,0.f,0.f};
        #pragma unroll
        for (int ks=0;ks<4;ks++){
            short8 b = W[ks*64 + lane];
            c0v = __builtin_amdgcn_mfma_f32_16x16x32_bf16(A0[ks], b, c0v, 0,0,0);
            c1v = __builtin_amdgcn_mfma_f32_16x16x32_bf16(A1[ks], b, c1v, 0,0,0);
        }
        #pragma unroll
        for (int r=0;r<4;r++){
            int row0 = rowbase + quad*4 + r;
            if (col == 0){
                sigmaArr[row0]    = c0v[r];
                sigmaArr[row0+16] = c1v[r];
            } else {
                buf[row0*LW      + 15 + col] = f2bf(c0v[r]);
                buf[(row0+16)*LW + 15 + col] = f2bf(c1v[r]);
            }
        }
        // SH basis (ray-uniform) -> cols 0..15 of this wave's rows
        const float dn = sqrtf(dx*dx+dy*dy+dz*dz);
        const float X = dx/dn, Y = dy/dn, Z = dz/dn;
        const float X2=X*X, Y2=Y*Y, Z2=Z*Z;
        float sh[16];
        sh[0]= 0.28209479177387814f;
        sh[1]=-0.48860251190291987f*Y;
        sh[2]= 0.48860251190291987f*Z;
        sh[3]=-0.48860251190291987f*X;
        sh[4]= 1.0925484305920792f*X*Y;
        sh[5]=-1.0925484305920792f*Y*Z;
        sh[6]= 0.94617469575756f*Z2 - 0.31539156525252f;
        sh[7]=-1.0925484305920792f*X*Z;
        sh[8]= 0.5462742152960396f*(X2-Y2);
        sh[9]= 0.5900435899266435f*Y*(-3.0f*X2+Y2);
        sh[10]=2.890611442640554f*X*Y*Z;
        sh[11]=0.4570457994644657f*Y*(1.0f-5.0f*Z2);
        sh[12]=0.3731763325901154f*Z*(5.0f*Z2-3.0f);
        sh[13]=0.4570457994644657f*X*(1.0f-5.0f*Z2);
        sh[14]=1.445305721320277f*Z*(X2-Y2);
        sh[15]=0.5900435899266435f*X*(-X2+3.0f*Y2);
        if (lane < 32){
            int row = rowbase + lane;
            #pragma unroll
            for (int k=0;k<16;k++) buf[row*LW + k] = f2bf(sh[k]);
        }
    }

    // CL1: 31(pad32) -> 64, relu
    {
        short8 a0 = *(const short8*)&buf[ar0*LW + quad*8];
        short8 a1 = *(const short8*)&buf[ar1*LW + quad*8];
        const short8* W = (const short8*)(Wp + OFF_CW0);
        #pragma unroll
        for (int nt=0; nt<4; nt++){
            short8 b = W[nt*64 + lane];
            floatx4 c0v = {0.f,0.f,0.f,0.f}, c1v = {0.f,0.f,0.f,0.f};
            c0v = __builtin_amdgcn_mfma_f32_16x16x32_bf16(a0, b, c0v, 0,0,0);
            c1v = __builtin_amdgcn_mfma_f32_16x16x32_bf16(a1, b, c1v, 0,0,0);
            #pragma unroll
            for (int r=0;r<4;r++){
                int row0 = rowbase + quad*4 + r;
                buf[row0*LW      + nt*16 + col] = f2bf(fmaxf(c0v[r],0.f));
                buf[(row0+16)*LW + nt*16 + col] = f2bf(fmaxf(c1v[r],0.f));
            }
        }
    }

    // CL2: 64 -> 64, relu
    {
        short8 A0[2], A1[2];
        #pragma unroll
        for (int ks=0;ks<2;ks++){
            A0[ks] = *(const short8*)&buf[ar0*LW + ks*32 + quad*8];
            A1[ks] = *(const short8*)&buf[ar1*LW + ks*32 + quad*8];
        }
        const short8* W = (const short8*)(Wp + OFF_CW1);
        #pragma unroll
        for (int nt=0; nt<4; nt++){
            floatx4 c0v = {0.f,0.f,0.f,0.f}, c1v = {0.f,0.f,0.f,0.f};
            #pragma unroll
            for (int ks=0;ks<2;ks++){
                short8 b = W[(nt*2+ks)*64 + lane];
                c0v = __builtin_amdgcn_mfma_f32_16x16x32_bf16(A0[ks], b, c0v, 0,0,0);
                c1v = __builtin_amdgcn_mfma_f32_16x16x32_bf16(A1[ks], b, c1v, 0,0,0);
            }
            #pragma unroll
            for (int r=0;r<4;r++){
                int row0 = rowbase + quad*4 + r;
                buf[row0*LW      + nt*16 + col] = f2bf(fmaxf(c0v[r],0.f));
                buf[(row0+16)*LW + nt*16 + col] = f2bf(fmaxf(c1v[r],0.f));
            }
        }
    }

    // CL3: 64 -> 3, no relu -> rgbArr
    {
        short8 A0[2], A1[2];
        #pragma unroll
        for (int ks=0;ks<2;ks++){
            A0[ks] = *(const short8*)&buf[ar0*LW + ks*32 + quad*8];
            A1[ks] = *(const short8*)&buf[ar1*LW + ks*32 + quad*8];
        }
        const short8* W = (const short8*)(Wp + OFF_CW2);
        floatx4 c0v = {0.f,0.f,0.f,0.f}, c1v = {0.f,0.f,0.f,0.f};
        #pragma unroll
        for (int ks=0;ks<2;ks++){
            short8 b = W[ks*64 + lane];
            c0v = __builtin_amdgcn_mfma_f32_16x16x32_bf16(A0[ks], b, c0v, 0,0,0);
            c1v = __builtin_amdgcn_mfma_f32_16x16x32_bf16(A1[ks], b, c1v, 0,0,0);
        }
        if (col < 3){
            #pragma unroll
            for (int r=0;r<4;r++){
                int row0 = rowbase + quad*4 + r;
                rgbArr[row0*3 + col]      = c0v[r];
                rgbArr[(row0+16)*3 + col] = c1v[r];
            }
        }
    }
    __syncthreads();   // the one cross-wave handoff: sigmaArr/rgbArr -> waves 0,1

    // ---------------- compositing (threads 0..127, sample = tid) ----------------
    float alpha = 0.f, rr = 0.f, rg = 0.f, rb = 0.f;
    if (tid < 128){
        float ts0 = nearv + (float)tid     * 0.0352f;
        float ts1 = nearv + (float)(tid+1) * 0.0352f;
        float tmid = 0.5f*(ts0+ts1);
        float dist = ts1 - ts0;
        float px = ox + tmid*dx, py = oy + tmid*dy, pz = oz + tmid*dz;
        bool mask = (fabsf(px)<=1.3f) && (fabsf(py)<=1.3f) && (fabsf(pz)<=1.3f)
                  && (tmid<=tmax) && (tmax>tmin);
        float sg = mask ? fmaxf(sigmaArr[tid], 0.f) : 0.f;
        alpha = 1.0f - expf(-sg*dist);
        if (mask){
            rr = 1.0f/(1.0f+expf(-rgbArr[tid*3+0]));
            rg = 1.0f/(1.0f+expf(-rgbArr[tid*3+1]));
            rb = 1.0f/(1.0f+expf(-rgbArr[tid*3+2]));
        }
    }
    float p = 1.0f - alpha + 1e-10f;
    #pragma unroll
    for (int off=1; off<64; off<<=1){
        float u = __shfl_up(p, off, 64);
        if (lane >= off) p *= u;
    }
    if (tid < 128 && lane == 63) wtot[wv] = p;
    float excl = __shfl_up(p, 1, 64);
    if (lane == 0) excl = 1.0f;
    __syncthreads();
    if (tid < 128){
        float T = excl;
        if (wv == 1) T *= wtot[0];
        float w = alpha * T;
        float v0 = wred64(w*rr);
        float v1 = wred64(w*rg);
        float v2 = wred64(w*rb);
        float v3 = wred64(w);
        if (lane == 0){
            partial[wv*4+0]=v0; partial[wv*4+1]=v1; partial[wv*4+2]=v2; partial[wv*4+3]=v3;
        }
    }
    __syncthreads();
    if (tid == 0){
        float acc = partial[3] + partial[7];
        float bg  = 1.0f - acc;
        out[ray*3+0] = partial[0] + partial[4] + bg;
        out[ray*3+1] = partial[1] + partial[5] + bg;
        out[ray*3+2] = partial[2] + partial[6] + bg;
    }
}

extern "C" void kernel_launch(void* const* d_in, const int* in_sizes, int n_in,
                              void* d_out, int out_size, void* d_ws, size_t ws_size,
                              hipStream_t stream){
    const float* rays_o = (const float*)d_in[0];
    const float* rays_d = (const float*)d_in[1];
    const float* Gxy    = (const float*)d_in[2];
    const float* Gxz    = (const float*)d_in[3];
    const float* Gyz    = (const float*)d_in[4];
    const float* F_grid = (const float*)d_in[5];
    const float* sW0    = (const float*)d_in[6];
    const float* sW1    = (const float*)d_in[7];
    const float* sW2    = (const float*)d_in[8];
    const float* cW0    = (const float*)d_in[9];
    const float* cW1    = (const float*)d_in[10];
    const float* cW2    = (const float*)d_in[11];

    short* Wp   = (short*)d_ws;                        // packed weights (59.4 KB)
    short* FvWS = Wp   + PACK_TOTAL;                   // 2048*128*32 bf16 = 16.78 MB
    short* Gp   = FvWS + (size_t)2048*128*32;          // padded bf16 triplanes, 7.08 MB
    short* Fg   = Gp   + (size_t)3*TRI_CELLS*32;       // bf16 F_grid, 2.1 MB

    pack_all<<<(PACK_TOTAL+255)/256, 256, 0, stream>>>(sW0,sW1,sW2,cW0,cW1,cW2,Wp);
    conv_tri<<<(TRI_TOTAL+255)/256, 256, 0, stream>>>(Gxy, Gxz, Gyz, Gp);
    conv_fg<<<(FG_TOTAL+255)/256, 256, 0, stream>>>(F_grid, Fg);
    interp2<<<2048, 256, 0, stream>>>(rays_o, rays_d, Gp, Fg, FvWS);
    nerf_mlp<<<2048, 256, 0, stream>>>(rays_o, rays_d, Wp, FvWS, (float*)d_out);
}